// Round 12
// baseline (405.695 us; speedup 1.0000x reference)
//
#include <hip/hip_runtime.h>
#include <stdint.h>

// ---------------- problem constants ----------------
constexpr int B  = 4, S = 8256, H = 768, NH = 12, HD = 64;
constexpr int M  = B * S;        // 33024 rows
constexpr int N3 = 3 * H;        // 2304 fused QKV cols
constexpr int NWG_GEMM = (M / 128) * (N3 / 128);   // 4644
constexpr int XQ8 = NWG_GEMM / 8, XR8 = NWG_GEMM % 8;
// workspace layout (bytes)
constexpr long XB_OFF   = 0;
constexpr long XB_BYTES = (long)M * H * 2;        // 50,724,864  f16 X
constexpr long W_OFF    = XB_OFF + XB_BYTES;
constexpr long W_BYTES  = (long)N3 * H * 2;       // 3,538,944   f16 Wq|Wk|Wv
constexpr long ROPE_OFF = W_OFF + W_BYTES;
constexpr long ROPE_BYTES = 128 * 32 * 2 * 4;     // 32 KB cos/sin table
constexpr long QKV_OFF  = ROPE_OFF + ROPE_BYTES;
constexpr long QKV_BYTES = (long)M * N3 * 2;      // 152,174,592 f16 QKV (rope applied)
constexpr long WS_NEEDED = QKV_OFF + QKV_BYTES;   // ~197 MB

typedef __attribute__((ext_vector_type(8))) _Float16 h8;        // 8 f16 = 4 VGPR (MFMA operand)
typedef __attribute__((ext_vector_type(8))) unsigned short us8;
typedef __attribute__((ext_vector_type(4))) float f4;

#define MFMA16(a,b,c) __builtin_amdgcn_mfma_f32_16x16x32_f16((a),(b),(c),0,0,0)
#define GLL16(gp, lp) __builtin_amdgcn_global_load_lds( \
    (__attribute__((address_space(1))) void*)(gp),      \
    (__attribute__((address_space(3))) void*)(lp), 16, 0, 0)
#define WAITV(N) asm volatile("s_waitcnt vmcnt(" #N ")" ::: "memory")

static __device__ __forceinline__ unsigned short f2h(float x) {  // RNE f32->f16
  _Float16 h = (_Float16)x;
  return __builtin_bit_cast(unsigned short, h);
}
static __device__ __forceinline__ f4 f4z() { f4 z = {0.f,0.f,0.f,0.f}; return z; }

// ================= prep: fp32->f16 converts + rope table =================
// blocks [0,12384): X   | [12384,13248): Wq/Wk/Wv | [13248,13264): rope table
__global__ __launch_bounds__(256) void prep_kernel(
    const float* __restrict__ X,
    const float* __restrict__ Wq, const float* __restrict__ Wk, const float* __restrict__ Wv,
    unsigned short* __restrict__ Xb, unsigned short* __restrict__ Wcat, float* __restrict__ rope)
{
  int bid = blockIdx.x;
  if (bid < 12384) {
    long base = (long)bid * 2048 + threadIdx.x * 8;
    float4 v0 = *(const float4*)(X + base);
    float4 v1 = *(const float4*)(X + base + 4);
    us8 o;
    o[0]=f2h(v0.x); o[1]=f2h(v0.y); o[2]=f2h(v0.z); o[3]=f2h(v0.w);
    o[4]=f2h(v1.x); o[5]=f2h(v1.y); o[6]=f2h(v1.z); o[7]=f2h(v1.w);
    *(us8*)(Xb + base) = o;
  } else if (bid < 13248) {
    int wb  = bid - 12384;
    int mat = wb / 288;
    int base = (wb % 288) * 2048 + threadIdx.x * 8;
    const float* src = (mat == 0) ? Wq : (mat == 1) ? Wk : Wv;
    float4 v0 = *(const float4*)(src + base);
    float4 v1 = *(const float4*)(src + base + 4);
    us8 o;
    o[0]=f2h(v0.x); o[1]=f2h(v0.y); o[2]=f2h(v0.z); o[3]=f2h(v0.w);
    o[4]=f2h(v1.x); o[5]=f2h(v1.y); o[6]=f2h(v1.z); o[7]=f2h(v1.w);
    *(us8*)(Wcat + (long)mat * 589824 + base) = o;
  } else {
    int t = (bid - 13248) * 256 + threadIdx.x;   // 4096 = 128 pos x 32 freq
    int p = t >> 5, i = t & 31;
    double ang = (double)p * pow(10000.0, -(double)i / 32.0);
    rope[2*t]   = (float)cos(ang);
    rope[2*t+1] = (float)sin(ang);
  }
}

// ================= fused QKV GEMM (+bias +RoPE epilogue) =================
// Y[M][2304] = X[M][768] @ Wcat[2304][768]^T ; 128x128 tile, BK=32, 4 waves.
// Depth-4 prefetch over a ring of 5 16KB buffers (80KB LDS, 2 blocks/CU):
// issue distance 4 phases x ~200cyc covers HBM latency (the r6 2-phase stalled
// ~600cyc/phase: p = 155 + (900 - p) -> p=527, util 29% == measured 26-29%).
// LDS slot layout: 128B slot = row pair (row r -> slot r>>1, half r&1),
// swizzle c ^= ((slot&3)<<4) -> 2-way bank aliasing (free, m136).
__global__ __launch_bounds__(256) void qkv_gemm(
    const unsigned short* __restrict__ Xb, const unsigned short* __restrict__ Wb,
    const float* __restrict__ bqp, const float* __restrict__ bkp, const float* __restrict__ bvp,
    const float* __restrict__ rope, unsigned short* __restrict__ QKV)
{
  __shared__ __align__(16) unsigned char lds[5][16384];  // ring: A [0,8K) | B [8K,16K)
  const int tid = threadIdx.x, lane = tid & 63, wid = tid >> 6;

  // bijective XCD-chunk remap (m204), nt-fastest within chunk (r6-proven: FETCH 206MB)
  const int bid0 = blockIdx.x;
  const int xcd = bid0 & 7, idx = bid0 >> 3;
  const int wgid = (xcd < XR8 ? xcd * (XQ8 + 1) : XR8 * (XQ8 + 1) + (xcd - XR8) * XQ8) + idx;
  const int mt = wgid / 18;
  const int nt = wgid % 18;
  const long m0 = (long)mt * 128;
  const int  n0 = nt * 128;
  const int wm = wid >> 1, wn = wid & 1;

  f4 acc[4][4];
  #pragma unroll
  for (int i = 0; i < 4; ++i)
    #pragma unroll
    for (int j = 0; j < 4; ++j) acc[i][j] = f4z();

  const char* Xc = (const char*)Xb;
  const char* Wc = (const char*)Wb;

// stage one BK=32 tile (A 8KB + B 8KB) into ring slot bi; 4 loads/thread
#define STAGE(bi, kt) do {                                                  \
    const int k0b_ = (kt) * 64;                                             \
    unsigned char* buf_ = lds[bi];                                          \
    _Pragma("unroll")                                                       \
    for (int i_ = 0; i_ < 2; ++i_) {                                        \
      const int o_  = i_ * 4096 + tid * 16;      /* linear dest byte */     \
      const int slot_ = o_ >> 7, d_ = o_ & 127;                             \
      const int row_ = slot_ * 2 + (d_ >> 6), c_ = d_ & 63;                 \
      const int cs_ = c_ ^ ((slot_ & 3) << 4);   /* pre-swizzled src */     \
      GLL16(Xc + (m0 + row_) * 1536 + k0b_ + cs_, buf_ + o_);               \
      GLL16(Wc + (long)(n0 + row_) * 1536 + k0b_ + cs_, buf_ + 8192 + o_);  \
    }                                                                       \
  } while (0)

// one BK=32 compute phase: 8 ds_read_b128 + 16 MFMA
#define COMPUTE(bi) do {                                                    \
    unsigned char* buf_ = lds[bi];                                          \
    h8 a_[4], b_[4];                                                        \
    const int kc_ = (lane >> 4) << 4;                                       \
    _Pragma("unroll")                                                       \
    for (int f_ = 0; f_ < 4; ++f_) {                                        \
      const int ra_ = wm * 64 + f_ * 16 + (lane & 15);                      \
      a_[f_] = *(const h8*)(buf_ + (ra_ >> 1) * 128 + (ra_ & 1) * 64        \
                            + (kc_ ^ (((ra_ >> 1) & 3) << 4)));             \
      const int rb_ = wn * 64 + f_ * 16 + (lane & 15);                      \
      b_[f_] = *(const h8*)(buf_ + 8192 + (rb_ >> 1) * 128 + (rb_ & 1) * 64 \
                            + (kc_ ^ (((rb_ >> 1) & 3) << 4)));             \
    }                                                                       \
    _Pragma("unroll")                                                       \
    for (int fm_ = 0; fm_ < 4; ++fm_)                                       \
      _Pragma("unroll")                                                     \
      for (int fn_ = 0; fn_ < 4; ++fn_)                                     \
        acc[fm_][fn_] = MFMA16(a_[fm_], b_[fn_], acc[fm_][fn_]);            \
  } while (0)

  STAGE(0, 0); STAGE(1, 1); STAGE(2, 2); STAGE(3, 3);   // 16 loads in flight
  #pragma unroll
  for (int i = 0; i < 24; ++i) {
    if (i + 4 < 24) STAGE((i + 4) % 5, i + 4);   // prev barrier freed slot (i-1)%5
    // wait = 4 x (#buffers issued after buffer i): forces buffer i resident
    if (i <= 19)      WAITV(16);
    else if (i == 20) WAITV(12);
    else if (i == 21) WAITV(8);
    else if (i == 22) WAITV(4);
    else              WAITV(0);
    __builtin_amdgcn_s_barrier();                 // all waves' loads drained
    asm volatile("" ::: "memory");
    COMPUTE(i % 5);
    asm volatile("" ::: "memory");
    __builtin_amdgcn_s_barrier();                 // all waves done reading slot i%5
  }
#undef STAGE
#undef COMPUTE

  // epilogue: bias + RoPE (wave spans exactly one head: 64 cols) + f16 store
  const int colb = n0 + wn * 64;
  const int sel = (colb >= 1536) ? 2 : (colb >= 768) ? 1 : 0;
  const float* bias = (sel == 0) ? bqp : (sel == 1) ? bkp : bvp;
  const int hcol = colb % 768;
  float bia[4];
  #pragma unroll
  for (int f = 0; f < 4; ++f) bia[f] = bias[hcol + f * 16 + (lane & 15)];

  #pragma unroll
  for (int fm = 0; fm < 4; ++fm) {
    #pragma unroll
    for (int reg = 0; reg < 4; ++reg) {
      const long m = m0 + wm * 64 + fm * 16 + ((lane >> 4) << 2) + reg;
      const int s = (int)(m % (long)S);
      const int pos = (s < 64) ? s : ((s - 64) & 127);
      unsigned short* orow = QKV + m * N3 + colb;
      if (sel < 2) {  // Q or K: rotate (d, d+32) pairs = (fn, fn+2) same lane
        #pragma unroll
        for (int f = 0; f < 2; ++f) {
          const int d1 = f * 16 + (lane & 15);
          const float c  = rope[(pos * 32 + d1) * 2];
          const float sn = rope[(pos * 32 + d1) * 2 + 1];
          const float x1 = acc[fm][f][reg]     + bia[f];
          const float x2 = acc[fm][f + 2][reg] + bia[f + 2];
          orow[f * 16 + (lane & 15)]       = f2h(x1 * c - x2 * sn);
          orow[(f + 2) * 16 + (lane & 15)] = f2h(x2 * c + x1 * sn);
        }
      } else {        // V: bias only
        #pragma unroll
        for (int f = 0; f < 4; ++f)
          orow[f * 16 + (lane & 15)] = f2h(acc[fm][f][reg] + bia[f]);
      }
    }
  }
}

// ================= attention (one block per (b, window, head)) =================
// 3-phase: [K->LDS once via global_load_lds, V->regs] | [QK^T from LDS] |
// [V^T ds_write overlaps softmax] | [PV]. K and V^T overlay the same 16 KB.
template <int T>
__global__ __launch_bounds__(256) void attn_kernel(
    const unsigned short* __restrict__ QKV, float* __restrict__ out)
{
  constexpr int NF  = T / 16;   // col fragments of scores
  constexpr int NKS = T / 32;   // k-steps of PV
  // phase 1: K [T rows][128 B] row-swizzled ; phase 2: V^T [64 d][256 B]
  __shared__ __align__(16) unsigned char sKV[16384];
  __shared__ __align__(16) unsigned char sP[4][8192];  // per-wave P [32][128] f16, swizzled

  const int tid = threadIdx.x, lane = tid & 63, w = tid >> 6;
  int bid = blockIdx.x;
  const int h = bid % NH; bid /= NH;
  long row0;
  if (T == 64) row0 = (long)bid * S;
  else { const int ww = bid % 64; const int b = bid / 64; row0 = (long)b * S + 64 + (long)ww * 128; }
  const unsigned short* Qb = QKV + row0 * N3 + h * HD;
  const unsigned short* Kb = Qb + H;
  const unsigned short* Vb = Qb + 2 * H;

  // ---- phase A: K -> LDS (linear dest, inverse-swizzled global src); V -> regs ----
  {
    const char* Kc = (const char*)Kb;
    #pragma unroll
    for (int i = 0; i < T / 32; ++i) {
      const int o = i * 4096 + tid * 16;        // linear dest byte
      const int row = o >> 7, cb = o & 127;
      const int csrc = cb ^ ((row & 7) << 4);
      GLL16(Kc + (long)row * (N3 * 2) + csrc, sKV + o);
    }
  }
  us8 va0, va1, vc0, vc1;
  const bool vload = (2 * lane + 1 < T);
  if (vload) {                                  // T14: issue early, write late
    const unsigned short* v0 = Vb + (long)(2 * lane) * N3 + w * 16;
    const unsigned short* v1 = v0 + N3;
    va0 = *(const us8*)(v0);  va1 = *(const us8*)(v0 + 8);
    vc0 = *(const us8*)(v1);  vc1 = *(const us8*)(v1 + 8);
  }
  __syncthreads();                              // K resident (full waitcnt drain)

  const bool active = (w * 32 < T);
  f4 acc[2][NF];
  if (active) {
    // Q fragments straight from global (A-layout: m=lane&15, k=(lane>>4)*8)
    h8 aq[2][2];
    #pragma unroll
    for (int fm = 0; fm < 2; ++fm)
      #pragma unroll
      for (int ks = 0; ks < 2; ++ks) {
        const long r = w * 32 + fm * 16 + (lane & 15);
        aq[fm][ks] = *(const h8*)(Qb + r * N3 + ks * 32 + ((lane >> 4) << 3));
      }
    #pragma unroll
    for (int i = 0; i < 2; ++i)
      #pragma unroll
      for (int f = 0; f < NF; ++f) acc[i][f] = f4z();

    // ---- S = Q K^T, K B-frags from LDS (shared across all waves) ----
    const int kb0 = (lane >> 4) << 4;
    #pragma unroll
    for (int f = 0; f < NF; ++f) {
      const int rk = f * 16 + (lane & 15);
      const int base = rk * 128, sw = (rk & 7) << 4;
      h8 b0 = *(const h8*)(sKV + base + (kb0 ^ sw));
      h8 b1 = *(const h8*)(sKV + base + ((64 + kb0) ^ sw));
      acc[0][f] = MFMA16(aq[0][0], b0, acc[0][f]);
      acc[0][f] = MFMA16(aq[0][1], b1, acc[0][f]);
      acc[1][f] = MFMA16(aq[1][0], b0, acc[1][f]);
      acc[1][f] = MFMA16(aq[1][1], b1, acc[1][f]);
    }
  }
  __syncthreads();                              // all waves done reading K

  // ---- phase B: V^T overlay write (conflict-free b32) + softmax -> sP ----
  if (vload) {
    #pragma unroll
    for (int i = 0; i < 8; ++i) {
      const int d = w * 16 + i, d2 = d + 8;
      *(unsigned*)(sKV + d  * 256 + ((4 * lane) ^ ((d  & 15) << 4))) = (unsigned)va0[i] | ((unsigned)vc0[i] << 16);
      *(unsigned*)(sKV + d2 * 256 + ((4 * lane) ^ ((d2 & 15) << 4))) = (unsigned)va1[i] | ((unsigned)vc1[i] << 16);
    }
  }
  if (active) {
    unsigned char* Pw = sP[w];
    #pragma unroll
    for (int fm = 0; fm < 2; ++fm) {
      #pragma unroll
      for (int reg = 0; reg < 4; ++reg) {
        float mx = -3.0e38f;
        #pragma unroll
        for (int f = 0; f < NF; ++f) mx = fmaxf(mx, acc[fm][f][reg]);
        mx = fmaxf(mx, __shfl_xor(mx, 1));
        mx = fmaxf(mx, __shfl_xor(mx, 2));
        mx = fmaxf(mx, __shfl_xor(mx, 4));
        mx = fmaxf(mx, __shfl_xor(mx, 8));
        float pv[NF], sum = 0.f;
        #pragma unroll
        for (int f = 0; f < NF; ++f) {
          const float p = __expf((acc[fm][f][reg] - mx) * 0.125f);  // /sqrt(64) folded in
          pv[f] = p; sum += p;
        }
        sum += __shfl_xor(sum, 1);
        sum += __shfl_xor(sum, 2);
        sum += __shfl_xor(sum, 4);
        sum += __shfl_xor(sum, 8);
        const float inv = 1.0f / sum;
        const int rloc = fm * 16 + ((lane >> 4) << 2) + reg;
        const int swz = (rloc & 7) << 4;
        #pragma unroll
        for (int f = 0; f < NF; ++f) {
          const int cb = (f * 16 + (lane & 15)) * 2;
          *(unsigned short*)(Pw + rloc * 256 + (cb ^ swz)) = f2h(pv[f] * inv);
        }
      }
    }
  }
  __syncthreads();                              // V^T ready

  if (active) {
    unsigned char* Pw = sP[w];
    // ---- ctx = P V ----
    f4 acc2[2][4];
    #pragma unroll
    for (int i = 0; i < 2; ++i)
      #pragma unroll
      for (int j = 0; j < 4; ++j) acc2[i][j] = f4z();

    #pragma unroll
    for (int ks = 0; ks < NKS; ++ks) {
      h8 pa[2], vb[4];
      const int kb = ks * 64 + ((lane >> 4) << 4);
      #pragma unroll
      for (int fm = 0; fm < 2; ++fm) {
        const int rp = fm * 16 + (lane & 15);
        pa[fm] = *(const h8*)(Pw + rp * 256 + (kb ^ ((rp & 7) << 4)));
      }
      #pragma unroll
      for (int df = 0; df < 4; ++df) {
        const int d = df * 16 + (lane & 15);
        vb[df] = *(const h8*)(sKV + d * 256 + (kb ^ ((d & 15) << 4)));
      }
      #pragma unroll
      for (int fm = 0; fm < 2; ++fm)
        #pragma unroll
        for (int df = 0; df < 4; ++df)
          acc2[fm][df] = MFMA16(pa[fm], vb[df], acc2[fm][df]);
    }

    // ---- write ctx fp32 to [B][S][H] ----
    float* ob = out + (row0 + w * 32) * H + h * HD;
    #pragma unroll
    for (int fm = 0; fm < 2; ++fm)
      #pragma unroll
      for (int df = 0; df < 4; ++df)
        #pragma unroll
        for (int reg = 0; reg < 4; ++reg) {
          const long r = fm * 16 + ((lane >> 4) << 2) + reg;
          const int c = df * 16 + (lane & 15);
          ob[r * H + c] = acc2[fm][df][reg];
        }
  }
}

// ================= launcher =================
extern "C" void kernel_launch(void* const* d_in, const int* in_sizes, int n_in,
                              void* d_out, int out_size, void* d_ws, size_t ws_size,
                              hipStream_t stream) {
  const float* X  = (const float*)d_in[0];
  // d_in[1] = attention_mask (unused by the reference math)
  const float* Wq = (const float*)d_in[2];
  const float* bq = (const float*)d_in[3];
  const float* Wk = (const float*)d_in[4];
  const float* bk = (const float*)d_in[5];
  const float* Wv = (const float*)d_in[6];
  const float* bv = (const float*)d_in[7];
  float* out = (float*)d_out;

  if ((long)ws_size < WS_NEEDED) return;  // clean fail if scratch too small

  char* ws = (char*)d_ws;
  unsigned short* Xb   = (unsigned short*)(ws + XB_OFF);
  unsigned short* Wcat = (unsigned short*)(ws + W_OFF);
  float*          rope = (float*)(ws + ROPE_OFF);
  unsigned short* QKV  = (unsigned short*)(ws + QKV_OFF);

  prep_kernel<<<13264, 256, 0, stream>>>(X, Wq, Wk, Wv, Xb, Wcat, rope);
  qkv_gemm<<<NWG_GEMM, 256, 0, stream>>>(Xb, Wcat, bq, bk, bv, rope, QKV);
  attn_kernel<64><<<B * NH, 256, 0, stream>>>(QKV, out);
  attn_kernel<128><<<B * 64 * NH, 256, 0, stream>>>(QKV, out);
}